// Round 4
// baseline (60400.555 us; speedup 1.0000x reference)
//
#include <hip/hip_runtime.h>
#include <math.h>
#include <type_traits>

#define BS   4
#define QLEN 2048
#define DIM  1024
#define NH   16
#define DH   64

// =====================================================================
// Kernel 1: projection GEMM  Out = (X @ W^T + bias) * scale
//   F64: accumulate in double (precision-critical Q/K path).
// =====================================================================
#define GBM 64
#define GBN 64
#define GBK 32

template<bool F64>
__global__ __launch_bounds__(256)
void qkv_gemm(const float* __restrict__ X, const float* __restrict__ W,
              const float* __restrict__ bias, float* __restrict__ Out,
              float scale)
{
    using acc_t = typename std::conditional<F64, double, float>::type;
    __shared__ float xs[GBM][GBK + 1];
    __shared__ float wsm[GBN][GBK + 1];

    const int m0 = blockIdx.y * GBM;
    const int n0 = blockIdx.x * GBN;
    const int tid = threadIdx.x;
    const int tx = tid & 15, ty = tid >> 4;

    acc_t acc[4][4];
    #pragma unroll
    for (int i = 0; i < 4; ++i)
        #pragma unroll
        for (int j = 0; j < 4; ++j) acc[i][j] = (acc_t)0;

    for (int k0 = 0; k0 < DIM; k0 += GBK) {
        #pragma unroll
        for (int p = 0; p < 2; ++p) {
            int f4 = tid + p * 256;
            int row = f4 >> 3;
            int c4 = (f4 & 7) << 2;
            float4 xv = *(const float4*)&X[(size_t)(m0 + row) * DIM + k0 + c4];
            xs[row][c4] = xv.x; xs[row][c4+1] = xv.y; xs[row][c4+2] = xv.z; xs[row][c4+3] = xv.w;
            float4 wv = *(const float4*)&W[(size_t)(n0 + row) * DIM + k0 + c4];
            wsm[row][c4] = wv.x; wsm[row][c4+1] = wv.y; wsm[row][c4+2] = wv.z; wsm[row][c4+3] = wv.w;
        }
        __syncthreads();
        #pragma unroll
        for (int kk = 0; kk < GBK; ++kk) {
            float a[4], bb[4];
            #pragma unroll
            for (int i = 0; i < 4; ++i) a[i] = xs[ty * 4 + i][kk];
            #pragma unroll
            for (int j = 0; j < 4; ++j) bb[j] = wsm[tx * 4 + j][kk];
            if (F64) {
                #pragma unroll
                for (int i = 0; i < 4; ++i)
                    #pragma unroll
                    for (int j = 0; j < 4; ++j)
                        acc[i][j] = (acc_t)fma((double)a[i], (double)bb[j], (double)acc[i][j]);
            } else {
                #pragma unroll
                for (int i = 0; i < 4; ++i)
                    #pragma unroll
                    for (int j = 0; j < 4; ++j)
                        acc[i][j] = (acc_t)fmaf(a[i], bb[j], (float)acc[i][j]);
            }
        }
        __syncthreads();
    }

    #pragma unroll
    for (int i = 0; i < 4; ++i) {
        int row = m0 + ty * 4 + i;
        int b_ = row >> 11;
        int s_ = row & 2047;
        int col0 = n0 + tx * 4;
        int h_ = col0 >> 6, d_ = col0 & 63;
        float4 o;
        #pragma unroll
        for (int j = 0; j < 4; ++j) {
            acc_t v = (acc[i][j] + (acc_t)bias[col0 + j]) * (acc_t)scale;
            (&o.x)[j] = (float)v;
        }
        *(float4*)&Out[((size_t)((b_ * NH + h_) * QLEN + s_)) * DH + d_] = o;
    }
}

// =====================================================================
// Kernel 2: fused attention core.
//   One block = (batch b, 16 q rows), 512 threads = (q 0..15) x (kt 0..31).
//   Head-summed weights live in 64 REGISTERS per thread. Lessons:
//     r1/r2: runtime-indexed asum[c*4+jj] -> alloca -> 28 GB scratch traffic.
//     r3:    global hsum RMW -> 68 GB HBM (L2/L3 don't absorb per-(h,c)
//            round-trips under 512 streaming blocks).
//   Fix: keep the c-loop rolled but force COMPILE-TIME asum indices via a
//   wave-uniform (SGPR) compare ladder -> SROA promotes all 64 slots.
// =====================================================================
#define QT  16
#define KC  128
#define NCH (QLEN / KC)   // 16

__global__ __launch_bounds__(512, 4)   // <=128 VGPR; LDS 79KB -> 2 blocks/CU
void attn_kernel(const float* __restrict__ Qm, const float* __restrict__ Km,
                 const float* __restrict__ Vm, const int* __restrict__ mask,
                 float* __restrict__ ctx_out, float* __restrict__ idx_out)
{
    __shared__ float qs[QT][DH];                  //  4 KB
    __shared__ float ks[KC][DH + 1];              // 33 KB (+1: conflict-free)
    __shared__ float vs[KC][DH];                  // 32 KB
    __shared__ __align__(8) float wch[QT][KC];    //  8 KB weights / reduce scratch
    __shared__ int   msk[KC];
    __shared__ float mq[QT];
    __shared__ float Lq[QT];

    double* dred = (double*)&wch[0][0];           // 512 doubles @ [0,4096)
    float*  fred = (float*)&wch[8][0];            // 512 floats  @ [4096,6144)
    int*    ired = (int*)&wch[8][0];              // argmax idx overlay

    const int b   = blockIdx.y;
    const int q0  = blockIdx.x * QT;
    const int tid = threadIdx.x;
    const int q   = tid >> 5;        // 0..15
    const int kt  = tid & 31;        // 0..31

    // head-summed softmax weights: slot r=(c*4+jj) -> k = c*128 + jj*32 + kt.
    // ALL accesses below use compile-time indices -> stays in VGPRs.
    float asum[64];
    #pragma unroll
    for (int r = 0; r < 64; ++r) asum[r] = 0.0f;

    #pragma unroll 1
    for (int h = 0; h < NH; ++h) {
        const float* Qh = Qm + (((size_t)b * NH + h) * QLEN + q0) * DH;
        const float* Kh = Km + ((size_t)b * NH + h) * QLEN * DH;
        const float* Vh = Vm + ((size_t)b * NH + h) * QLEN * DH;

        {   // stage q-tile 16x64 (already includes 1/sqrt(dh))
            int i2 = tid << 1;
            int row = i2 >> 6, col = i2 & 63;
            *(float2*)&qs[row][col] = *(const float2*)&Qh[(size_t)row * DH + col];
        }

        // ---------------- pass 1: per-row running (max, sumexp) ----------------
        float m = -INFINITY;
        float l = 0.0f;
        #pragma unroll 1
        for (int c = 0; c < NCH; ++c) {
            #pragma unroll
            for (int p = 0; p < 4; ++p) {
                int f4 = tid + p * 512;
                int row = f4 >> 4, c4 = (f4 & 15) << 2;
                float4 kv = *(const float4*)&Kh[(size_t)(c * KC + row) * DH + c4];
                ks[row][c4] = kv.x; ks[row][c4+1] = kv.y; ks[row][c4+2] = kv.z; ks[row][c4+3] = kv.w;
            }
            if (tid < KC) msk[tid] = mask[b * QLEN + c * KC + tid];
            __syncthreads();

            float sacc[4] = {0.f, 0.f, 0.f, 0.f};
            #pragma unroll
            for (int d0 = 0; d0 < DH; d0 += 8) {
                float qr[8];
                #pragma unroll
                for (int dd = 0; dd < 8; ++dd) qr[dd] = qs[q][d0 + dd];
                #pragma unroll
                for (int jj = 0; jj < 4; ++jj)
                    #pragma unroll
                    for (int dd = 0; dd < 8; ++dd)
                        sacc[jj] = fmaf(qr[dd], ks[kt + 32 * jj][d0 + dd], sacc[jj]);
            }
            #pragma unroll
            for (int jj = 0; jj < 4; ++jj) {
                float s = msk[kt + 32 * jj] ? sacc[jj] : -INFINITY;
                if (s > m)              { l = l * __expf(m - s) + 1.0f; m = s; }
                else if (s > -INFINITY) { l += __expf(s - m); }
            }
            __syncthreads();
        }

        // reduce (m,l) across the 32 kt-threads of each q-row (f64 combine)
        dred[q * 32 + kt] = (double)l;
        fred[q * 32 + kt] = m;
        __syncthreads();
        if (kt == 0) {
            float M = -INFINITY;
            for (int i = 0; i < 32; ++i) M = fmaxf(M, fred[q * 32 + i]);
            double L = 0.0;
            for (int i = 0; i < 32; ++i) {
                float mi = fred[q * 32 + i];
                if (mi > -INFINITY) L += dred[q * 32 + i] * exp((double)(mi - M));
            }
            mq[q] = M;
            Lq[q] = (float)L;
        }
        __syncthreads();

        // ---------------- pass 2: weights -> asum (static regs) -> PV ----------
        float cv0 = 0.f, cv1 = 0.f;
        const float Mv = mq[q], Lv = Lq[q];
        #pragma unroll 1
        for (int c = 0; c < NCH; ++c) {
            #pragma unroll
            for (int p = 0; p < 4; ++p) {
                int f4 = tid + p * 512;
                int row = f4 >> 4, c4 = (f4 & 15) << 2;
                float4 kv = *(const float4*)&Kh[(size_t)(c * KC + row) * DH + c4];
                ks[row][c4] = kv.x; ks[row][c4+1] = kv.y; ks[row][c4+2] = kv.z; ks[row][c4+3] = kv.w;
                *(float4*)&vs[row][c4] = *(const float4*)&Vh[(size_t)(c * KC + row) * DH + c4];
            }
            if (tid < KC) msk[tid] = mask[b * QLEN + c * KC + tid];
            __syncthreads();

            float sacc[4] = {0.f, 0.f, 0.f, 0.f};
            #pragma unroll
            for (int d0 = 0; d0 < DH; d0 += 8) {
                float qr[8];
                #pragma unroll
                for (int dd = 0; dd < 8; ++dd) qr[dd] = qs[q][d0 + dd];
                #pragma unroll
                for (int jj = 0; jj < 4; ++jj)
                    #pragma unroll
                    for (int dd = 0; dd < 8; ++dd)
                        sacc[jj] = fmaf(qr[dd], ks[kt + 32 * jj][d0 + dd], sacc[jj]);
            }
            float w4[4];
            #pragma unroll
            for (int jj = 0; jj < 4; ++jj) {
                float s = msk[kt + 32 * jj] ? sacc[jj] : -INFINITY;
                float w = expf(s - Mv) / Lv;          // accurate exp + true division
                wch[q][kt + 32 * jj] = w;
                w4[jj] = w;
            }
            // static-index accumulate: wave-uniform SGPR compare ladder
            {
                int cu = __builtin_amdgcn_readfirstlane(c);
                #pragma unroll
                for (int r = 0; r < NCH; ++r) {
                    if (r == cu) {
                        asum[r * 4 + 0] += w4[0];
                        asum[r * 4 + 1] += w4[1];
                        asum[r * 4 + 2] += w4[2];
                        asum[r * 4 + 3] += w4[3];
                    }
                }
            }
            __syncthreads();

            #pragma unroll 8
            for (int k = 0; k < KC; ++k) {
                float w = wch[q][k];
                cv0 = fmaf(w, vs[k][kt],      cv0);
                cv1 = fmaf(w, vs[k][kt + 32], cv1);
            }
            __syncthreads();
        }
        float* cp = ctx_out + ((size_t)(b * QLEN + q0 + q)) * DIM + h * DH;
        cp[kt]      = cv0;
        cp[kt + 32] = cv1;
    }

    // ---------------- argmax of head-summed weights (first-index ties) ------
    float bv = -1.0f; int bk_ = 0;
    #pragma unroll
    for (int r = 0; r < 64; ++r) {   // k strictly increasing in r -> '>' keeps first
        int k = (r >> 2) * KC + (r & 3) * 32 + kt;
        if (asum[r] > bv) { bv = asum[r]; bk_ = k; }
    }
    __syncthreads();
    dred[q * 32 + kt] = (double)bv;
    ired[q * 32 + kt] = bk_;
    __syncthreads();
    if (kt == 0) {
        double BV = -1.0; int BKi = 1 << 30;
        for (int i = 0; i < 32; ++i) {
            double v = dred[q * 32 + i];
            int kk = ired[q * 32 + i];
            if (v > BV || (v == BV && kk < BKi)) { BV = v; BKi = kk; }
        }
        idx_out[b * QLEN + q0 + q] = (float)BKi;
    }
}

// =====================================================================
// Kernel 3: in-place output projection  IO = IO @ Wo^T + bo
// =====================================================================
#define OPROWS 16

__global__ __launch_bounds__(512, 2)
void outproj_kernel(float* __restrict__ IO, const float* __restrict__ Wo,
                    const float* __restrict__ bo)
{
    __shared__ float ctxs[OPROWS][DIM];    // 64 KB
    __shared__ float wos[64][129];         // 33 KB, +1 pad

    const int m0 = blockIdx.x * OPROWS;
    const int tid = threadIdx.x;
    const int q = tid >> 5, kt = tid & 31;

    #pragma unroll
    for (int p = 0; p < 8; ++p) {
        int f4 = tid + p * 512;
        int row = f4 >> 8;
        int c4 = (f4 & 255) << 2;
        *(float4*)&ctxs[row][c4] = *(const float4*)&IO[(size_t)(m0 + row) * DIM + c4];
    }
    __syncthreads();

    #pragma unroll 1
    for (int oc = 0; oc < DIM / 64; ++oc) {
        float a0 = 0.f, a1 = 0.f;
        #pragma unroll 1
        for (int d0 = 0; d0 < DIM; d0 += 128) {
            #pragma unroll
            for (int p = 0; p < 4; ++p) {
                int f4 = tid + p * 512;
                int row = f4 >> 5, c4 = (f4 & 31) << 2;
                float4 wv = *(const float4*)&Wo[(size_t)(oc * 64 + row) * DIM + d0 + c4];
                wos[row][c4] = wv.x; wos[row][c4+1] = wv.y; wos[row][c4+2] = wv.z; wos[row][c4+3] = wv.w;
            }
            __syncthreads();
            #pragma unroll 8
            for (int dd = 0; dd < 128; ++dd) {
                float cv = ctxs[q][d0 + dd];
                a0 = fmaf(cv, wos[kt][dd],      a0);
                a1 = fmaf(cv, wos[32 + kt][dd], a1);
            }
            __syncthreads();
        }
        int o0 = oc * 64 + kt;
        IO[(size_t)(m0 + q) * DIM + o0]      = a0 + bo[o0];
        IO[(size_t)(m0 + q) * DIM + o0 + 32] = a1 + bo[o0 + 32];
    }
}

// =====================================================================
extern "C" void kernel_launch(void* const* d_in, const int* in_sizes, int n_in,
                              void* d_out, int out_size, void* d_ws, size_t ws_size,
                              hipStream_t stream)
{
    (void)in_sizes; (void)n_in; (void)out_size; (void)ws_size;
    const float* query = (const float*)d_in[0];
    const int*   mask  = (const int*)  d_in[1];
    const float* Wq = (const float*)d_in[2];
    const float* bq = (const float*)d_in[3];
    const float* Wk = (const float*)d_in[4];
    const float* bk = (const float*)d_in[5];
    const float* Wv = (const float*)d_in[6];
    const float* bv = (const float*)d_in[7];
    const float* Wo = (const float*)d_in[8];
    const float* bo = (const float*)d_in[9];

    float* out = (float*)d_out;
    const size_t NTOK = (size_t)BS * QLEN;     // 8192
    float* Qw = (float*)d_ws;                  // ws: 3 x 32 MB = 96 MB
    float* Kw = Qw + NTOK * DIM;
    float* Vw = Kw + NTOK * DIM;

    dim3 gemm_grid(DIM / GBN, (BS * QLEN) / GBM);   // (16, 128)
    qkv_gemm<true><<<gemm_grid, dim3(256), 0, stream>>>(query, Wq, bq, Qw, 0.125f);
    qkv_gemm<true><<<gemm_grid, dim3(256), 0, stream>>>(query, Wk, bk, Kw, 1.0f);
    qkv_gemm<false><<<gemm_grid, dim3(256), 0, stream>>>(query, Wv, bv, Vw, 1.0f);

    float* ctx = out;                  // reuse out region as ctx scratch
    float* idx = out + NTOK * DIM;     // argmax output tail
    attn_kernel<<<dim3(QLEN / QT, BS), dim3(512), 0, stream>>>(Qw, Kw, Vw, mask, ctx, idx);

    outproj_kernel<<<dim3(NTOK / OPROWS), dim3(512), 0, stream>>>(out, Wo, bo);
}

// Round 5
// 21455.492 us; speedup vs baseline: 2.8152x; 2.8152x over previous
//
#include <hip/hip_runtime.h>
#include <math.h>
#include <type_traits>

#define BS   4
#define QLEN 2048
#define DIM  1024
#define NH   16
#define DH   64

// =====================================================================
// Kernel 1: projection GEMM  Out = (X @ W^T + bias) * scale
//   F64: accumulate in double (precision-critical Q/K path).
// =====================================================================
#define GBM 64
#define GBN 64
#define GBK 32

template<bool F64>
__global__ __launch_bounds__(256)
void qkv_gemm(const float* __restrict__ X, const float* __restrict__ W,
              const float* __restrict__ bias, float* __restrict__ Out,
              float scale)
{
    using acc_t = typename std::conditional<F64, double, float>::type;
    __shared__ float xs[GBM][GBK + 1];
    __shared__ float wsm[GBN][GBK + 1];

    const int m0 = blockIdx.y * GBM;
    const int n0 = blockIdx.x * GBN;
    const int tid = threadIdx.x;
    const int tx = tid & 15, ty = tid >> 4;

    acc_t acc[4][4];
    #pragma unroll
    for (int i = 0; i < 4; ++i)
        #pragma unroll
        for (int j = 0; j < 4; ++j) acc[i][j] = (acc_t)0;

    for (int k0 = 0; k0 < DIM; k0 += GBK) {
        #pragma unroll
        for (int p = 0; p < 2; ++p) {
            int f4 = tid + p * 256;
            int row = f4 >> 3;
            int c4 = (f4 & 7) << 2;
            float4 xv = *(const float4*)&X[(size_t)(m0 + row) * DIM + k0 + c4];
            xs[row][c4] = xv.x; xs[row][c4+1] = xv.y; xs[row][c4+2] = xv.z; xs[row][c4+3] = xv.w;
            float4 wv = *(const float4*)&W[(size_t)(n0 + row) * DIM + k0 + c4];
            wsm[row][c4] = wv.x; wsm[row][c4+1] = wv.y; wsm[row][c4+2] = wv.z; wsm[row][c4+3] = wv.w;
        }
        __syncthreads();
        #pragma unroll
        for (int kk = 0; kk < GBK; ++kk) {
            float a[4], bb[4];
            #pragma unroll
            for (int i = 0; i < 4; ++i) a[i] = xs[ty * 4 + i][kk];
            #pragma unroll
            for (int j = 0; j < 4; ++j) bb[j] = wsm[tx * 4 + j][kk];
            if (F64) {
                #pragma unroll
                for (int i = 0; i < 4; ++i)
                    #pragma unroll
                    for (int j = 0; j < 4; ++j)
                        acc[i][j] = (acc_t)fma((double)a[i], (double)bb[j], (double)acc[i][j]);
            } else {
                #pragma unroll
                for (int i = 0; i < 4; ++i)
                    #pragma unroll
                    for (int j = 0; j < 4; ++j)
                        acc[i][j] = (acc_t)fmaf(a[i], bb[j], (float)acc[i][j]);
            }
        }
        __syncthreads();
    }

    #pragma unroll
    for (int i = 0; i < 4; ++i) {
        int row = m0 + ty * 4 + i;
        int b_ = row >> 11;
        int s_ = row & 2047;
        int col0 = n0 + tx * 4;
        int h_ = col0 >> 6, d_ = col0 & 63;
        float4 o;
        #pragma unroll
        for (int j = 0; j < 4; ++j) {
            acc_t v = (acc[i][j] + (acc_t)bias[col0 + j]) * (acc_t)scale;
            (&o.x)[j] = (float)v;
        }
        *(float4*)&Out[((size_t)((b_ * NH + h_) * QLEN + s_)) * DH + d_] = o;
    }
}

// =====================================================================
// Kernel 2: fused attention (ctx only, NO argmax state).
//   One block = (batch b, 16 q rows), 512 threads = (q 0..15) x (kt 0..31).
//   Per-thread state is scalars + small fully-unrolled temporaries only.
//   Rounds 1-4 lesson: ANY 64-slot per-thread accumulator array indexed
//   from a rolled loop -> alloca -> scratch -> tens of GB of HBM traffic.
//   The head-sum/argmax lives in kernel 2b instead.
//   Writes per-(q,h) softmax stats (M, L) to MLbuf for kernel 2b.
// =====================================================================
#define QT  16
#define KC  128
#define NCH (QLEN / KC)   // 16

__global__ __launch_bounds__(512, 4)
void attn_kernel(const float* __restrict__ Qm, const float* __restrict__ Km,
                 const float* __restrict__ Vm, const int* __restrict__ mask,
                 float* __restrict__ ctx_out, float* __restrict__ MLbuf)
{
    __shared__ float qs[QT][DH];                  //  4 KB
    __shared__ float ks[KC][DH + 1];              // 33 KB (+1: conflict-free)
    __shared__ float vs[KC][DH];                  // 32 KB
    __shared__ __align__(8) float wch[QT][KC];    //  8 KB weights / reduce scratch
    __shared__ int   msk[KC];
    __shared__ float mq[QT];
    __shared__ float Lq[QT];

    double* dred = (double*)&wch[0][0];           // 512 doubles @ [0,4096)
    float*  fred = (float*)&wch[8][0];            // 512 floats  @ [4096,6144)

    const int b   = blockIdx.y;
    const int q0  = blockIdx.x * QT;
    const int tid = threadIdx.x;
    const int q   = tid >> 5;        // 0..15
    const int kt  = tid & 31;        // 0..31

    #pragma unroll 1
    for (int h = 0; h < NH; ++h) {
        const float* Qh = Qm + (((size_t)b * NH + h) * QLEN + q0) * DH;
        const float* Kh = Km + ((size_t)b * NH + h) * QLEN * DH;
        const float* Vh = Vm + ((size_t)b * NH + h) * QLEN * DH;

        {   // stage q-tile 16x64 (already includes 1/sqrt(dh))
            int i2 = tid << 1;
            int row = i2 >> 6, col = i2 & 63;
            *(float2*)&qs[row][col] = *(const float2*)&Qh[(size_t)row * DH + col];
        }

        // ---------------- pass 1: per-row running (max, sumexp) ----------------
        float m = -INFINITY;
        float l = 0.0f;
        #pragma unroll 1
        for (int c = 0; c < NCH; ++c) {
            #pragma unroll
            for (int p = 0; p < 4; ++p) {
                int f4 = tid + p * 512;
                int row = f4 >> 4, c4 = (f4 & 15) << 2;
                float4 kv = *(const float4*)&Kh[(size_t)(c * KC + row) * DH + c4];
                ks[row][c4] = kv.x; ks[row][c4+1] = kv.y; ks[row][c4+2] = kv.z; ks[row][c4+3] = kv.w;
            }
            if (tid < KC) msk[tid] = mask[b * QLEN + c * KC + tid];
            __syncthreads();

            float sacc[4] = {0.f, 0.f, 0.f, 0.f};
            #pragma unroll
            for (int d0 = 0; d0 < DH; d0 += 8) {
                float qr[8];
                #pragma unroll
                for (int dd = 0; dd < 8; ++dd) qr[dd] = qs[q][d0 + dd];
                #pragma unroll
                for (int jj = 0; jj < 4; ++jj)
                    #pragma unroll
                    for (int dd = 0; dd < 8; ++dd)
                        sacc[jj] = fmaf(qr[dd], ks[kt + 32 * jj][d0 + dd], sacc[jj]);
            }
            #pragma unroll
            for (int jj = 0; jj < 4; ++jj) {
                float s = msk[kt + 32 * jj] ? sacc[jj] : -INFINITY;
                if (s > m)              { l = l * __expf(m - s) + 1.0f; m = s; }
                else if (s > -INFINITY) { l += __expf(s - m); }
            }
            __syncthreads();
        }

        // reduce (m,l) across the 32 kt-threads of each q-row (f64 combine)
        dred[q * 32 + kt] = (double)l;
        fred[q * 32 + kt] = m;
        __syncthreads();
        if (kt == 0) {
            float M = -INFINITY;
            for (int i = 0; i < 32; ++i) M = fmaxf(M, fred[q * 32 + i]);
            double L = 0.0;
            for (int i = 0; i < 32; ++i) {
                float mi = fred[q * 32 + i];
                if (mi > -INFINITY) L += dred[q * 32 + i] * exp((double)(mi - M));
            }
            mq[q] = M;
            Lq[q] = (float)L;
            // side-channel for the hsum/argmax kernel
            float* mlp = MLbuf + (((size_t)(b * QLEN + q0 + q)) * NH + h) * 2;
            mlp[0] = M;
            mlp[1] = (float)L;
        }
        __syncthreads();

        // ---------------- pass 2: weights -> PV ----------
        float cv0 = 0.f, cv1 = 0.f;
        const float Mv = mq[q], Lv = Lq[q];
        #pragma unroll 1
        for (int c = 0; c < NCH; ++c) {
            #pragma unroll
            for (int p = 0; p < 4; ++p) {
                int f4 = tid + p * 512;
                int row = f4 >> 4, c4 = (f4 & 15) << 2;
                float4 kv = *(const float4*)&Kh[(size_t)(c * KC + row) * DH + c4];
                ks[row][c4] = kv.x; ks[row][c4+1] = kv.y; ks[row][c4+2] = kv.z; ks[row][c4+3] = kv.w;
                *(float4*)&vs[row][c4] = *(const float4*)&Vh[(size_t)(c * KC + row) * DH + c4];
            }
            if (tid < KC) msk[tid] = mask[b * QLEN + c * KC + tid];
            __syncthreads();

            float sacc[4] = {0.f, 0.f, 0.f, 0.f};
            #pragma unroll
            for (int d0 = 0; d0 < DH; d0 += 8) {
                float qr[8];
                #pragma unroll
                for (int dd = 0; dd < 8; ++dd) qr[dd] = qs[q][d0 + dd];
                #pragma unroll
                for (int jj = 0; jj < 4; ++jj)
                    #pragma unroll
                    for (int dd = 0; dd < 8; ++dd)
                        sacc[jj] = fmaf(qr[dd], ks[kt + 32 * jj][d0 + dd], sacc[jj]);
            }
            #pragma unroll
            for (int jj = 0; jj < 4; ++jj) {
                float s = msk[kt + 32 * jj] ? sacc[jj] : -INFINITY;
                float w = expf(s - Mv) / Lv;          // accurate exp + true division
                wch[q][kt + 32 * jj] = w;
            }
            __syncthreads();

            #pragma unroll 8
            for (int k = 0; k < KC; ++k) {
                float w = wch[q][k];
                cv0 = fmaf(w, vs[k][kt],      cv0);
                cv1 = fmaf(w, vs[k][kt + 32], cv1);
            }
            __syncthreads();
        }
        float* cp = ctx_out + ((size_t)(b * QLEN + q0 + q)) * DIM + h * DH;
        cp[kt]      = cv0;
        cp[kt + 32] = cv1;
    }
}

// =====================================================================
// Kernel 2b: head-summed softmax weights -> argmax.
//   Loop order c OUTER, h INNER: the only live accumulators are 4 NAMED
//   scalars per c-iteration (h0..h3) + running (bv,bk). No arrays -> no
//   alloca -> no scratch. Recomputes scores from Q,K with (M,L) from
//   MLbuf; identical ops (expf, /L) and identical h-ascending summation
//   order as the round-2/3 passing argmax -> bit-identical hsum values.
// =====================================================================
__global__ __launch_bounds__(512, 4)
void hsum_argmax_kernel(const float* __restrict__ Qm, const float* __restrict__ Km,
                        const int* __restrict__ mask, const float* __restrict__ MLbuf,
                        float* __restrict__ idx_out)
{
    __shared__ float qs[QT][DH];                  //  4 KB (restaged per h)
    __shared__ float ks[KC][DH + 1];              // 33 KB
    __shared__ float Mh[NH][QT];                  //  1 KB
    __shared__ float Lh[NH][QT];                  //  1 KB
    __shared__ int   msk[KC];
    __shared__ float rv[512];
    __shared__ int   ri[512];

    const int b   = blockIdx.y;
    const int q0  = blockIdx.x * QT;
    const int tid = threadIdx.x;
    const int q   = tid >> 5;        // 0..15
    const int kt  = tid & 31;        // 0..31

    if (tid < NH * QT) {             // load per-(q,h) softmax stats
        int h = tid >> 4, qq = tid & 15;
        const float* mlp = MLbuf + (((size_t)(b * QLEN + q0 + qq)) * NH + h) * 2;
        Mh[h][qq] = mlp[0];
        Lh[h][qq] = mlp[1];
    }

    float bv = -1.0f; int bk = 0;
    #pragma unroll 1
    for (int c = 0; c < NCH; ++c) {
        float h0 = 0.f, h1 = 0.f, h2 = 0.f, h3 = 0.f;   // named scalar slots
        #pragma unroll 1
        for (int h = 0; h < NH; ++h) {
            __syncthreads();          // previous readers of ks/qs/msk done
            #pragma unroll
            for (int p = 0; p < 4; ++p) {
                int f4 = tid + p * 512;
                int row = f4 >> 4, c4 = (f4 & 15) << 2;
                const float* Kh = Km + ((size_t)b * NH + h) * QLEN * DH;
                float4 kv = *(const float4*)&Kh[(size_t)(c * KC + row) * DH + c4];
                ks[row][c4] = kv.x; ks[row][c4+1] = kv.y; ks[row][c4+2] = kv.z; ks[row][c4+3] = kv.w;
            }
            if (tid < 256) {          // stage q-tile for head h
                int row = tid >> 4, c4 = (tid & 15) << 2;
                const float* Qh = Qm + (((size_t)b * NH + h) * QLEN + q0) * DH;
                *(float4*)&qs[row][c4] = *(const float4*)&Qh[(size_t)row * DH + c4];
            }
            if (h == 0 && tid < KC) msk[tid] = mask[b * QLEN + c * KC + tid];
            __syncthreads();

            float sacc[4] = {0.f, 0.f, 0.f, 0.f};
            #pragma unroll
            for (int d0 = 0; d0 < DH; d0 += 8) {
                float qr[8];
                #pragma unroll
                for (int dd = 0; dd < 8; ++dd) qr[dd] = qs[q][d0 + dd];
                #pragma unroll
                for (int jj = 0; jj < 4; ++jj)
                    #pragma unroll
                    for (int dd = 0; dd < 8; ++dd)
                        sacc[jj] = fmaf(qr[dd], ks[kt + 32 * jj][d0 + dd], sacc[jj]);
            }
            const float Mv = Mh[h][q], Lv = Lh[h][q];
            float s0 = msk[kt]      ? sacc[0] : -INFINITY;
            float s1 = msk[kt + 32] ? sacc[1] : -INFINITY;
            float s2 = msk[kt + 64] ? sacc[2] : -INFINITY;
            float s3 = msk[kt + 96] ? sacc[3] : -INFINITY;
            h0 += expf(s0 - Mv) / Lv;
            h1 += expf(s1 - Mv) / Lv;
            h2 += expf(s2 - Mv) / Lv;
            h3 += expf(s3 - Mv) / Lv;
        }
        // k ascending across (c, slot) for fixed kt -> '>' keeps first index
        int kbase = c * KC + kt;
        if (h0 > bv) { bv = h0; bk = kbase;      }
        if (h1 > bv) { bv = h1; bk = kbase + 32; }
        if (h2 > bv) { bv = h2; bk = kbase + 64; }
        if (h3 > bv) { bv = h3; bk = kbase + 96; }
    }

    rv[tid] = bv;
    ri[tid] = bk;
    __syncthreads();
    if (kt == 0) {                   // min-index tie-break across the 32 kt threads
        float BV = -1.0f; int BKi = 1 << 30;
        for (int i = 0; i < 32; ++i) {
            float v = rv[q * 32 + i];
            int  kk = ri[q * 32 + i];
            if (v > BV || (v == BV && kk < BKi)) { BV = v; BKi = kk; }
        }
        idx_out[b * QLEN + q0 + q] = (float)BKi;
    }
}

// =====================================================================
// Kernel 3: in-place output projection  IO = IO @ Wo^T + bo
// =====================================================================
#define OPROWS 16

__global__ __launch_bounds__(512, 2)
void outproj_kernel(float* __restrict__ IO, const float* __restrict__ Wo,
                    const float* __restrict__ bo)
{
    __shared__ float ctxs[OPROWS][DIM];    // 64 KB
    __shared__ float wos[64][129];         // 33 KB, +1 pad

    const int m0 = blockIdx.x * OPROWS;
    const int tid = threadIdx.x;
    const int q = tid >> 5, kt = tid & 31;

    #pragma unroll
    for (int p = 0; p < 8; ++p) {
        int f4 = tid + p * 512;
        int row = f4 >> 8;
        int c4 = (f4 & 255) << 2;
        *(float4*)&ctxs[row][c4] = *(const float4*)&IO[(size_t)(m0 + row) * DIM + c4];
    }
    __syncthreads();

    #pragma unroll 1
    for (int oc = 0; oc < DIM / 64; ++oc) {
        float a0 = 0.f, a1 = 0.f;
        #pragma unroll 1
        for (int d0 = 0; d0 < DIM; d0 += 128) {
            #pragma unroll
            for (int p = 0; p < 4; ++p) {
                int f4 = tid + p * 512;
                int row = f4 >> 5, c4 = (f4 & 31) << 2;
                float4 wv = *(const float4*)&Wo[(size_t)(oc * 64 + row) * DIM + d0 + c4];
                wos[row][c4] = wv.x; wos[row][c4+1] = wv.y; wos[row][c4+2] = wv.z; wos[row][c4+3] = wv.w;
            }
            __syncthreads();
            #pragma unroll 8
            for (int dd = 0; dd < 128; ++dd) {
                float cv = ctxs[q][d0 + dd];
                a0 = fmaf(cv, wos[kt][dd],      a0);
                a1 = fmaf(cv, wos[32 + kt][dd], a1);
            }
            __syncthreads();
        }
        int o0 = oc * 64 + kt;
        IO[(size_t)(m0 + q) * DIM + o0]      = a0 + bo[o0];
        IO[(size_t)(m0 + q) * DIM + o0 + 32] = a1 + bo[o0 + 32];
    }
}

// =====================================================================
extern "C" void kernel_launch(void* const* d_in, const int* in_sizes, int n_in,
                              void* d_out, int out_size, void* d_ws, size_t ws_size,
                              hipStream_t stream)
{
    (void)in_sizes; (void)n_in; (void)out_size; (void)ws_size;
    const float* query = (const float*)d_in[0];
    const int*   mask  = (const int*)  d_in[1];
    const float* Wq = (const float*)d_in[2];
    const float* bq = (const float*)d_in[3];
    const float* Wk = (const float*)d_in[4];
    const float* bk = (const float*)d_in[5];
    const float* Wv = (const float*)d_in[6];
    const float* bv = (const float*)d_in[7];
    const float* Wo = (const float*)d_in[8];
    const float* bo = (const float*)d_in[9];

    float* out = (float*)d_out;
    const size_t NTOK = (size_t)BS * QLEN;     // 8192
    float* Qw = (float*)d_ws;                  // ws: 3 x 32 MB + 1 MB
    float* Kw = Qw + NTOK * DIM;
    float* Vw = Kw + NTOK * DIM;
    float* ML = Vw + NTOK * DIM;               // [NTOK][NH][2] f32

    dim3 gemm_grid(DIM / GBN, (BS * QLEN) / GBM);   // (16, 128)
    qkv_gemm<true><<<gemm_grid, dim3(256), 0, stream>>>(query, Wq, bq, Qw, 0.125f);
    qkv_gemm<true><<<gemm_grid, dim3(256), 0, stream>>>(query, Wk, bk, Kw, 1.0f);
    qkv_gemm<false><<<gemm_grid, dim3(256), 0, stream>>>(query, Wv, bv, Vw, 1.0f);

    float* ctx = out;                  // reuse out region as ctx scratch
    float* idx = out + NTOK * DIM;     // argmax output tail
    attn_kernel<<<dim3(QLEN / QT, BS), dim3(512), 0, stream>>>(Qw, Kw, Vw, mask, ctx, ML);
    hsum_argmax_kernel<<<dim3(QLEN / QT, BS), dim3(512), 0, stream>>>(Qw, Kw, mask, ML, idx);
    outproj_kernel<<<dim3(NTOK / OPROWS), dim3(512), 0, stream>>>(out, Wo, bo);
}

// Round 6
// 5644.397 us; speedup vs baseline: 10.7010x; 3.8012x over previous
//
#include <hip/hip_runtime.h>
#include <math.h>
#include <type_traits>

#define BS   4
#define QLEN 2048
#define DIM  1024
#define NH   16
#define DH   64

// =====================================================================
// Kernel 1: projection GEMM  Out = (X @ W^T + bias) * scale
//   F64: accumulate in double (precision-critical Q/K path).
// =====================================================================
#define GBM 64
#define GBN 64
#define GBK 32

template<bool F64>
__global__ __launch_bounds__(256)
void qkv_gemm(const float* __restrict__ X, const float* __restrict__ W,
              const float* __restrict__ bias, float* __restrict__ Out,
              float scale)
{
    using acc_t = typename std::conditional<F64, double, float>::type;
    __shared__ float xs[GBM][GBK + 1];
    __shared__ float wsm[GBN][GBK + 1];

    const int m0 = blockIdx.y * GBM;
    const int n0 = blockIdx.x * GBN;
    const int tid = threadIdx.x;
    const int tx = tid & 15, ty = tid >> 4;

    acc_t acc[4][4];
    #pragma unroll
    for (int i = 0; i < 4; ++i)
        #pragma unroll
        for (int j = 0; j < 4; ++j) acc[i][j] = (acc_t)0;

    for (int k0 = 0; k0 < DIM; k0 += GBK) {
        #pragma unroll
        for (int p = 0; p < 2; ++p) {
            int f4 = tid + p * 256;
            int row = f4 >> 3;
            int c4 = (f4 & 7) << 2;
            float4 xv = *(const float4*)&X[(size_t)(m0 + row) * DIM + k0 + c4];
            xs[row][c4] = xv.x; xs[row][c4+1] = xv.y; xs[row][c4+2] = xv.z; xs[row][c4+3] = xv.w;
            float4 wv = *(const float4*)&W[(size_t)(n0 + row) * DIM + k0 + c4];
            wsm[row][c4] = wv.x; wsm[row][c4+1] = wv.y; wsm[row][c4+2] = wv.z; wsm[row][c4+3] = wv.w;
        }
        __syncthreads();
        #pragma unroll
        for (int kk = 0; kk < GBK; ++kk) {
            float a[4], bb[4];
            #pragma unroll
            for (int i = 0; i < 4; ++i) a[i] = xs[ty * 4 + i][kk];
            #pragma unroll
            for (int j = 0; j < 4; ++j) bb[j] = wsm[tx * 4 + j][kk];
            if (F64) {
                #pragma unroll
                for (int i = 0; i < 4; ++i)
                    #pragma unroll
                    for (int j = 0; j < 4; ++j)
                        acc[i][j] = (acc_t)fma((double)a[i], (double)bb[j], (double)acc[i][j]);
            } else {
                #pragma unroll
                for (int i = 0; i < 4; ++i)
                    #pragma unroll
                    for (int j = 0; j < 4; ++j)
                        acc[i][j] = (acc_t)fmaf(a[i], bb[j], (float)acc[i][j]);
            }
        }
        __syncthreads();
    }

    #pragma unroll
    for (int i = 0; i < 4; ++i) {
        int row = m0 + ty * 4 + i;
        int b_ = row >> 11;
        int s_ = row & 2047;
        int col0 = n0 + tx * 4;
        int h_ = col0 >> 6, d_ = col0 & 63;
        float4 o;
        #pragma unroll
        for (int j = 0; j < 4; ++j) {
            acc_t v = (acc[i][j] + (acc_t)bias[col0 + j]) * (acc_t)scale;
            (&o.x)[j] = (float)v;
        }
        *(float4*)&Out[((size_t)((b_ * NH + h_) * QLEN + s_)) * DH + d_] = o;
    }
}

// =====================================================================
// Kernel 2: flash attention (single pass over K/V, online softmax).
//   One block = (batch b, 32 q rows), 512 threads = (q 0..31) x (kt 0..15).
//   91 KB LDS -> exactly 1 block/CU (round-5 lesson: 2 blocks/CU thrashed
//   L2/L3, FETCH went 5.4->25.8 GB; r2's 1-block/CU regime was faster).
//   Per-thread state: scalars only (m, l, cv0..cv3) - rounds 1-4 lesson.
//   Row reductions via 16-lane shfl_xor butterflies, no LDS round-trip.
//   Scores use the same ascending-d fmaf chain as kernel 2b -> the stored
//   M is bit-identical to 2b's recompute; L differs ~1e-7 rel (uniform
//   per head-row, cancels in the head-sum ordering).
// =====================================================================
#define QT  16            // q-tile of the hsum/argmax kernel (unchanged)
#define QT2 32            // q-tile of the flash kernel
#define KC  128
#define NCH (QLEN / KC)   // 16

__global__ __launch_bounds__(512, 2)
void attn_kernel(const float* __restrict__ Qm, const float* __restrict__ Km,
                 const float* __restrict__ Vm, const int* __restrict__ mask,
                 float* __restrict__ ctx_out, float* __restrict__ MLbuf)
{
    __shared__ float qs[QT2][DH + 4];    //  8.5 KB (+4: float4-aligned, bank-spread)
    __shared__ float ks[KC][DH + 4];     // 34 KB
    __shared__ float vs[KC][DH];         // 32 KB
    __shared__ float wch[QT2][KC + 1];   // 16.1 KB (+1: 4 q-groups on distinct banks)
    __shared__ int   msk[KC];

    const int b   = blockIdx.y;
    const int q0  = blockIdx.x * QT2;
    const int tid = threadIdx.x;
    const int q   = tid >> 4;        // 0..31
    const int kt  = tid & 15;        // 0..15

    #pragma unroll 1
    for (int h = 0; h < NH; ++h) {
        const float* Qh = Qm + (((size_t)b * NH + h) * QLEN + q0) * DH;
        const float* Kh = Km + ((size_t)b * NH + h) * QLEN * DH;
        const float* Vh = Vm + ((size_t)b * NH + h) * QLEN * DH;

        {   // stage q-tile 32x64 (already includes 1/sqrt(dh)); covered by c=0 barrier
            int row = tid >> 4, c4 = (tid & 15) << 2;
            *(float4*)&qs[row][c4] = *(const float4*)&Qh[(size_t)row * DH + c4];
        }

        float m = -INFINITY, l = 0.0f;
        float cv0 = 0.f, cv1 = 0.f, cv2 = 0.f, cv3 = 0.f;   // ctx cols 4*kt .. 4*kt+3

        #pragma unroll 1
        for (int c = 0; c < NCH; ++c) {
            #pragma unroll
            for (int p = 0; p < 4; ++p) {
                int f4 = tid + p * 512;
                int row = f4 >> 4, c4 = (f4 & 15) << 2;
                *(float4*)&ks[row][c4] = *(const float4*)&Kh[(size_t)(c * KC + row) * DH + c4];
                *(float4*)&vs[row][c4] = *(const float4*)&Vh[(size_t)(c * KC + row) * DH + c4];
            }
            if (tid < KC) msk[tid] = mask[b * QLEN + c * KC + tid];
            __syncthreads();

            // ---- scores: 8 k's per thread (k = kt + 16*jj), ascending-d chain ----
            float s[8];
            #pragma unroll
            for (int jj = 0; jj < 8; ++jj) s[jj] = 0.f;
            #pragma unroll
            for (int d0 = 0; d0 < DH; d0 += 4) {
                float4 qv = *(const float4*)&qs[q][d0];
                #pragma unroll
                for (int jj = 0; jj < 8; ++jj) {
                    float4 kv = *(const float4*)&ks[kt + 16 * jj][d0];
                    s[jj] = fmaf(qv.x, kv.x, s[jj]);
                    s[jj] = fmaf(qv.y, kv.y, s[jj]);
                    s[jj] = fmaf(qv.z, kv.z, s[jj]);
                    s[jj] = fmaf(qv.w, kv.w, s[jj]);
                }
            }
            float mm = -INFINITY;
            #pragma unroll
            for (int jj = 0; jj < 8; ++jj) {
                s[jj] = msk[kt + 16 * jj] ? s[jj] : -INFINITY;
                mm = fmaxf(mm, s[jj]);
            }
            // row max across the 16 kt threads (lanes of one 16-lane group)
            #pragma unroll
            for (int off = 1; off < 16; off <<= 1)
                mm = fmaxf(mm, __shfl_xor(mm, off, 64));

            float m_new = fmaxf(m, mm);
            float scale = (m_new > -INFINITY) ? __expf(m - m_new) : 0.0f;
            float lsum = 0.f;
            #pragma unroll
            for (int jj = 0; jj < 8; ++jj) {
                float w = (s[jj] > -INFINITY) ? __expf(s[jj] - m_new) : 0.0f;
                wch[q][kt + 16 * jj] = w;
                lsum += w;
            }
            l = l * scale + lsum;
            cv0 *= scale; cv1 *= scale; cv2 *= scale; cv3 *= scale;
            m = m_new;
            __syncthreads();   // wch ready

            // ---- PV: ctx[q][4kt..4kt+3] += w[k] * V[k][.] ----
            #pragma unroll 8
            for (int k = 0; k < KC; ++k) {
                float w = wch[q][k];
                float4 vv = *(const float4*)&vs[k][kt << 2];
                cv0 = fmaf(w, vv.x, cv0);
                cv1 = fmaf(w, vv.y, cv1);
                cv2 = fmaf(w, vv.z, cv2);
                cv3 = fmaf(w, vv.w, cv3);
            }
            __syncthreads();   // before next chunk overwrites ks/vs/wch
        }

        // row sum of l across the 16 kt threads
        float L = l;
        #pragma unroll
        for (int off = 1; off < 16; off <<= 1)
            L += __shfl_xor(L, off, 64);

        float* cp = ctx_out + ((size_t)(b * QLEN + q0 + q)) * DIM + h * DH;
        float4 o = make_float4(cv0 / L, cv1 / L, cv2 / L, cv3 / L);
        *(float4*)&cp[kt << 2] = o;

        if (kt == 0) {   // side-channel for the hsum/argmax kernel
            float* mlp = MLbuf + (((size_t)(b * QLEN + q0 + q)) * NH + h) * 2;
            mlp[0] = m;
            mlp[1] = L;
        }
    }
}

// =====================================================================
// Kernel 2b: head-summed softmax weights -> argmax (UNCHANGED from the
//   passing round-5 version; sole producer of output 1).
//   Loop order c OUTER, h INNER; only named scalar accumulators.
// =====================================================================
__global__ __launch_bounds__(512, 4)
void hsum_argmax_kernel(const float* __restrict__ Qm, const float* __restrict__ Km,
                        const int* __restrict__ mask, const float* __restrict__ MLbuf,
                        float* __restrict__ idx_out)
{
    __shared__ float qs[QT][DH];                  //  4 KB (restaged per h)
    __shared__ float ks[KC][DH + 1];              // 33 KB
    __shared__ float Mh[NH][QT];                  //  1 KB
    __shared__ float Lh[NH][QT];                  //  1 KB
    __shared__ int   msk[KC];
    __shared__ float rv[512];
    __shared__ int   ri[512];

    const int b   = blockIdx.y;
    const int q0  = blockIdx.x * QT;
    const int tid = threadIdx.x;
    const int q   = tid >> 5;        // 0..15
    const int kt  = tid & 31;        // 0..31

    if (tid < NH * QT) {             // load per-(q,h) softmax stats
        int h = tid >> 4, qq = tid & 15;
        const float* mlp = MLbuf + (((size_t)(b * QLEN + q0 + qq)) * NH + h) * 2;
        Mh[h][qq] = mlp[0];
        Lh[h][qq] = mlp[1];
    }

    float bv = -1.0f; int bk = 0;
    #pragma unroll 1
    for (int c = 0; c < NCH; ++c) {
        float h0 = 0.f, h1 = 0.f, h2 = 0.f, h3 = 0.f;   // named scalar slots
        #pragma unroll 1
        for (int h = 0; h < NH; ++h) {
            __syncthreads();          // previous readers of ks/qs/msk done
            #pragma unroll
            for (int p = 0; p < 4; ++p) {
                int f4 = tid + p * 512;
                int row = f4 >> 4, c4 = (f4 & 15) << 2;
                const float* Kh = Km + ((size_t)b * NH + h) * QLEN * DH;
                float4 kv = *(const float4*)&Kh[(size_t)(c * KC + row) * DH + c4];
                ks[row][c4] = kv.x; ks[row][c4+1] = kv.y; ks[row][c4+2] = kv.z; ks[row][c4+3] = kv.w;
            }
            if (tid < 256) {          // stage q-tile for head h
                int row = tid >> 4, c4 = (tid & 15) << 2;
                const float* Qh = Qm + (((size_t)b * NH + h) * QLEN + q0) * DH;
                *(float4*)&qs[row][c4] = *(const float4*)&Qh[(size_t)row * DH + c4];
            }
            if (h == 0 && tid < KC) msk[tid] = mask[b * QLEN + c * KC + tid];
            __syncthreads();

            float sacc[4] = {0.f, 0.f, 0.f, 0.f};
            #pragma unroll
            for (int d0 = 0; d0 < DH; d0 += 8) {
                float qr[8];
                #pragma unroll
                for (int dd = 0; dd < 8; ++dd) qr[dd] = qs[q][d0 + dd];
                #pragma unroll
                for (int jj = 0; jj < 4; ++jj)
                    #pragma unroll
                    for (int dd = 0; dd < 8; ++dd)
                        sacc[jj] = fmaf(qr[dd], ks[kt + 32 * jj][d0 + dd], sacc[jj]);
            }
            const float Mv = Mh[h][q], Lv = Lh[h][q];
            float s0 = msk[kt]      ? sacc[0] : -INFINITY;
            float s1 = msk[kt + 32] ? sacc[1] : -INFINITY;
            float s2 = msk[kt + 64] ? sacc[2] : -INFINITY;
            float s3 = msk[kt + 96] ? sacc[3] : -INFINITY;
            h0 += expf(s0 - Mv) / Lv;
            h1 += expf(s1 - Mv) / Lv;
            h2 += expf(s2 - Mv) / Lv;
            h3 += expf(s3 - Mv) / Lv;
        }
        // k ascending across (c, slot) for fixed kt -> '>' keeps first index
        int kbase = c * KC + kt;
        if (h0 > bv) { bv = h0; bk = kbase;      }
        if (h1 > bv) { bv = h1; bk = kbase + 32; }
        if (h2 > bv) { bv = h2; bk = kbase + 64; }
        if (h3 > bv) { bv = h3; bk = kbase + 96; }
    }

    rv[tid] = bv;
    ri[tid] = bk;
    __syncthreads();
    if (kt == 0) {                   // min-index tie-break across the 32 kt threads
        float BV = -1.0f; int BKi = 1 << 30;
        for (int i = 0; i < 32; ++i) {
            float v = rv[q * 32 + i];
            int  kk = ri[q * 32 + i];
            if (v > BV || (v == BV && kk < BKi)) { BV = v; BKi = kk; }
        }
        idx_out[b * QLEN + q0 + q] = (float)BKi;
    }
}

// =====================================================================
// Kernel 3: in-place output projection  IO = IO @ Wo^T + bo
// =====================================================================
#define OPROWS 16

__global__ __launch_bounds__(512, 2)
void outproj_kernel(float* __restrict__ IO, const float* __restrict__ Wo,
                    const float* __restrict__ bo)
{
    __shared__ float ctxs[OPROWS][DIM];    // 64 KB
    __shared__ float wos[64][129];         // 33 KB, +1 pad

    const int m0 = blockIdx.x * OPROWS;
    const int tid = threadIdx.x;
    const int q = tid >> 5, kt = tid & 31;

    #pragma unroll
    for (int p = 0; p < 8; ++p) {
        int f4 = tid + p * 512;
        int row = f4 >> 8;
        int c4 = (f4 & 255) << 2;
        *(float4*)&ctxs[row][c4] = *(const float4*)&IO[(size_t)(m0 + row) * DIM + c4];
    }
    __syncthreads();

    #pragma unroll 1
    for (int oc = 0; oc < DIM / 64; ++oc) {
        float a0 = 0.f, a1 = 0.f;
        #pragma unroll 1
        for (int d0 = 0; d0 < DIM; d0 += 128) {
            #pragma unroll
            for (int p = 0; p < 4; ++p) {
                int f4 = tid + p * 512;
                int row = f4 >> 5, c4 = (f4 & 31) << 2;
                float4 wv = *(const float4*)&Wo[(size_t)(oc * 64 + row) * DIM + d0 + c4];
                wos[row][c4] = wv.x; wos[row][c4+1] = wv.y; wos[row][c4+2] = wv.z; wos[row][c4+3] = wv.w;
            }
            __syncthreads();
            #pragma unroll 8
            for (int dd = 0; dd < 128; ++dd) {
                float cv = ctxs[q][d0 + dd];
                a0 = fmaf(cv, wos[kt][dd],      a0);
                a1 = fmaf(cv, wos[32 + kt][dd], a1);
            }
            __syncthreads();
        }
        int o0 = oc * 64 + kt;
        IO[(size_t)(m0 + q) * DIM + o0]      = a0 + bo[o0];
        IO[(size_t)(m0 + q) * DIM + o0 + 32] = a1 + bo[o0 + 32];
    }
}

// =====================================================================
extern "C" void kernel_launch(void* const* d_in, const int* in_sizes, int n_in,
                              void* d_out, int out_size, void* d_ws, size_t ws_size,
                              hipStream_t stream)
{
    (void)in_sizes; (void)n_in; (void)out_size; (void)ws_size;
    const float* query = (const float*)d_in[0];
    const int*   mask  = (const int*)  d_in[1];
    const float* Wq = (const float*)d_in[2];
    const float* bq = (const float*)d_in[3];
    const float* Wk = (const float*)d_in[4];
    const float* bk = (const float*)d_in[5];
    const float* Wv = (const float*)d_in[6];
    const float* bv = (const float*)d_in[7];
    const float* Wo = (const float*)d_in[8];
    const float* bo = (const float*)d_in[9];

    float* out = (float*)d_out;
    const size_t NTOK = (size_t)BS * QLEN;     // 8192
    float* Qw = (float*)d_ws;                  // ws: 3 x 32 MB + 1 MB
    float* Kw = Qw + NTOK * DIM;
    float* Vw = Kw + NTOK * DIM;
    float* ML = Vw + NTOK * DIM;               // [NTOK][NH][2] f32

    dim3 gemm_grid(DIM / GBN, (BS * QLEN) / GBM);   // (16, 128)
    qkv_gemm<true><<<gemm_grid, dim3(256), 0, stream>>>(query, Wq, bq, Qw, 0.125f);
    qkv_gemm<true><<<gemm_grid, dim3(256), 0, stream>>>(query, Wk, bk, Kw, 1.0f);
    qkv_gemm<false><<<gemm_grid, dim3(256), 0, stream>>>(query, Wv, bv, Vw, 1.0f);

    float* ctx = out;                  // reuse out region as ctx scratch
    float* idx = out + NTOK * DIM;     // argmax output tail
    attn_kernel<<<dim3(QLEN / QT2, BS), dim3(512), 0, stream>>>(Qw, Kw, Vw, mask, ctx, ML);
    hsum_argmax_kernel<<<dim3(QLEN / QT, BS), dim3(512), 0, stream>>>(Qw, Kw, mask, ML, idx);
    outproj_kernel<<<dim3(NTOK / OPROWS), dim3(512), 0, stream>>>(out, Wo, bo);
}

// Round 7
// 5637.090 us; speedup vs baseline: 10.7148x; 1.0013x over previous
//
#include <hip/hip_runtime.h>
#include <math.h>
#include <type_traits>

#define BS   4
#define QLEN 2048
#define DIM  1024
#define NH   16
#define DH   64

// =====================================================================
// Kernel 1: projection GEMM  Out = (X @ W^T + bias) * scale
//   F64: accumulate in double (precision-critical Q/K path).
// =====================================================================
#define GBM 64
#define GBN 64
#define GBK 32

template<bool F64>
__global__ __launch_bounds__(256)
void qkv_gemm(const float* __restrict__ X, const float* __restrict__ W,
              const float* __restrict__ bias, float* __restrict__ Out,
              float scale)
{
    using acc_t = typename std::conditional<F64, double, float>::type;
    __shared__ float xs[GBM][GBK + 1];
    __shared__ float wsm[GBN][GBK + 1];

    const int m0 = blockIdx.y * GBM;
    const int n0 = blockIdx.x * GBN;
    const int tid = threadIdx.x;
    const int tx = tid & 15, ty = tid >> 4;

    acc_t acc[4][4];
    #pragma unroll
    for (int i = 0; i < 4; ++i)
        #pragma unroll
        for (int j = 0; j < 4; ++j) acc[i][j] = (acc_t)0;

    for (int k0 = 0; k0 < DIM; k0 += GBK) {
        #pragma unroll
        for (int p = 0; p < 2; ++p) {
            int f4 = tid + p * 256;
            int row = f4 >> 3;
            int c4 = (f4 & 7) << 2;
            float4 xv = *(const float4*)&X[(size_t)(m0 + row) * DIM + k0 + c4];
            xs[row][c4] = xv.x; xs[row][c4+1] = xv.y; xs[row][c4+2] = xv.z; xs[row][c4+3] = xv.w;
            float4 wv = *(const float4*)&W[(size_t)(n0 + row) * DIM + k0 + c4];
            wsm[row][c4] = wv.x; wsm[row][c4+1] = wv.y; wsm[row][c4+2] = wv.z; wsm[row][c4+3] = wv.w;
        }
        __syncthreads();
        #pragma unroll
        for (int kk = 0; kk < GBK; ++kk) {
            float a[4], bb[4];
            #pragma unroll
            for (int i = 0; i < 4; ++i) a[i] = xs[ty * 4 + i][kk];
            #pragma unroll
            for (int j = 0; j < 4; ++j) bb[j] = wsm[tx * 4 + j][kk];
            if (F64) {
                #pragma unroll
                for (int i = 0; i < 4; ++i)
                    #pragma unroll
                    for (int j = 0; j < 4; ++j)
                        acc[i][j] = (acc_t)fma((double)a[i], (double)bb[j], (double)acc[i][j]);
            } else {
                #pragma unroll
                for (int i = 0; i < 4; ++i)
                    #pragma unroll
                    for (int j = 0; j < 4; ++j)
                        acc[i][j] = (acc_t)fmaf(a[i], bb[j], (float)acc[i][j]);
            }
        }
        __syncthreads();
    }

    #pragma unroll
    for (int i = 0; i < 4; ++i) {
        int row = m0 + ty * 4 + i;
        int b_ = row >> 11;
        int s_ = row & 2047;
        int col0 = n0 + tx * 4;
        int h_ = col0 >> 6, d_ = col0 & 63;
        float4 o;
        #pragma unroll
        for (int j = 0; j < 4; ++j) {
            acc_t v = (acc[i][j] + (acc_t)bias[col0 + j]) * (acc_t)scale;
            (&o.x)[j] = (float)v;
        }
        *(float4*)&Out[((size_t)((b_ * NH + h_) * QLEN + s_)) * DH + d_] = o;
    }
}

// =====================================================================
// Kernel 2: flash attention (single pass over K/V, online softmax).
//   One block = (batch b, 32 q rows), 512 threads = (q 0..31) x (kt 0..15).
//   93.7 KB LDS -> 1 block/CU (r5 lesson: 2 blocks/CU thrash L3).
//   STORE_S: additionally stores the masked scores (f32, bit-identical to
//   the hsum recompute chain) to Sbuf for the streaming hsum/argmax kernel.
// =====================================================================
#define QT  16            // q-tile of the fallback hsum/argmax kernel
#define QT2 32            // q-tile of the flash kernel
#define KC  128
#define NCH (QLEN / KC)   // 16

template<bool STORE_S>
__global__ __launch_bounds__(512, 1)   // LDS caps at 1 block/CU anyway; no VGPR cap
void attn_kernel(const float* __restrict__ Qm, const float* __restrict__ Km,
                 const float* __restrict__ Vm, const int* __restrict__ mask,
                 float* __restrict__ ctx_out, float* __restrict__ MLbuf,
                 float* __restrict__ Sbuf)
{
    __shared__ float qs[QT2][DH + 4];    //  8.5 KB
    __shared__ float ks[KC][DH + 4];     // 34 KB
    __shared__ float vs[KC][DH];         // 32 KB
    __shared__ float wch[QT2][KC + 1];   // 16.1 KB
    __shared__ int   msk[KC];

    const int b   = blockIdx.y;
    const int q0  = blockIdx.x * QT2;
    const int tid = threadIdx.x;
    const int q   = tid >> 4;        // 0..31
    const int kt  = tid & 15;        // 0..15

    #pragma unroll 1
    for (int h = 0; h < NH; ++h) {
        const float* Qh = Qm + (((size_t)b * NH + h) * QLEN + q0) * DH;
        const float* Kh = Km + ((size_t)b * NH + h) * QLEN * DH;
        const float* Vh = Vm + ((size_t)b * NH + h) * QLEN * DH;
        float* srow = STORE_S
            ? Sbuf + (((size_t)(b * NH + h)) * QLEN + (q0 + q)) * QLEN
            : nullptr;

        {   // stage q-tile 32x64 (already includes 1/sqrt(dh)); covered by c=0 barrier
            int row = tid >> 4, c4 = (tid & 15) << 2;
            *(float4*)&qs[row][c4] = *(const float4*)&Qh[(size_t)row * DH + c4];
        }

        float m = -INFINITY, l = 0.0f;
        float cv0 = 0.f, cv1 = 0.f, cv2 = 0.f, cv3 = 0.f;   // ctx cols 4*kt .. 4*kt+3

        #pragma unroll 1
        for (int c = 0; c < NCH; ++c) {
            #pragma unroll
            for (int p = 0; p < 4; ++p) {
                int f4 = tid + p * 512;
                int row = f4 >> 4, c4 = (f4 & 15) << 2;
                *(float4*)&ks[row][c4] = *(const float4*)&Kh[(size_t)(c * KC + row) * DH + c4];
                *(float4*)&vs[row][c4] = *(const float4*)&Vh[(size_t)(c * KC + row) * DH + c4];
            }
            if (tid < KC) msk[tid] = mask[b * QLEN + c * KC + tid];
            __syncthreads();

            // ---- scores: 8 k's per thread (k = kt + 16*jj), ascending-d chain ----
            float s[8];
            #pragma unroll
            for (int jj = 0; jj < 8; ++jj) s[jj] = 0.f;
            #pragma unroll
            for (int d0 = 0; d0 < DH; d0 += 4) {
                float4 qv = *(const float4*)&qs[q][d0];
                #pragma unroll
                for (int jj = 0; jj < 8; ++jj) {
                    float4 kv = *(const float4*)&ks[kt + 16 * jj][d0];
                    s[jj] = fmaf(qv.x, kv.x, s[jj]);
                    s[jj] = fmaf(qv.y, kv.y, s[jj]);
                    s[jj] = fmaf(qv.z, kv.z, s[jj]);
                    s[jj] = fmaf(qv.w, kv.w, s[jj]);
                }
            }
            float mm = -INFINITY;
            #pragma unroll
            for (int jj = 0; jj < 8; ++jj) {
                s[jj] = msk[kt + 16 * jj] ? s[jj] : -INFINITY;
                mm = fmaxf(mm, s[jj]);
            }
            if (STORE_S) {   // masked scores, bit-identical to the old recompute
                #pragma unroll
                for (int jj = 0; jj < 8; ++jj)
                    srow[c * KC + kt + 16 * jj] = s[jj];
            }
            // row max across the 16 kt threads (lanes of one 16-lane group)
            #pragma unroll
            for (int off = 1; off < 16; off <<= 1)
                mm = fmaxf(mm, __shfl_xor(mm, off, 64));

            float m_new = fmaxf(m, mm);
            float scale = (m_new > -INFINITY) ? __expf(m - m_new) : 0.0f;
            float lsum = 0.f;
            #pragma unroll
            for (int jj = 0; jj < 8; ++jj) {
                float w = (s[jj] > -INFINITY) ? __expf(s[jj] - m_new) : 0.0f;
                wch[q][kt + 16 * jj] = w;
                lsum += w;
            }
            l = l * scale + lsum;
            cv0 *= scale; cv1 *= scale; cv2 *= scale; cv3 *= scale;
            m = m_new;
            __syncthreads();   // wch ready

            // ---- PV: ctx[q][4kt..4kt+3] += w[k] * V[k][.] ----
            #pragma unroll 8
            for (int k = 0; k < KC; ++k) {
                float w = wch[q][k];
                float4 vv = *(const float4*)&vs[k][kt << 2];
                cv0 = fmaf(w, vv.x, cv0);
                cv1 = fmaf(w, vv.y, cv1);
                cv2 = fmaf(w, vv.z, cv2);
                cv3 = fmaf(w, vv.w, cv3);
            }
            __syncthreads();   // before next chunk overwrites ks/vs/wch
        }

        // row sum of l across the 16 kt threads
        float L = l;
        #pragma unroll
        for (int off = 1; off < 16; off <<= 1)
            L += __shfl_xor(L, off, 64);

        float* cp = ctx_out + ((size_t)(b * QLEN + q0 + q)) * DIM + h * DH;
        float4 o = make_float4(cv0 / L, cv1 / L, cv2 / L, cv3 / L);
        *(float4*)&cp[kt << 2] = o;

        if (kt == 0) {   // side-channel for the hsum/argmax kernels
            float* mlp = MLbuf + (((size_t)(b * QLEN + q0 + q)) * NH + h) * 2;
            mlp[0] = m;
            mlp[1] = L;
        }
    }
}

// =====================================================================
// Kernel 2b-fast: streaming hsum + argmax from stored scores.
//   One block = one (b,q) row, 256 threads. Reads 16 x 8KB score rows,
//   w = expf(s - M)/L in the same h-ascending order as the recompute
//   version -> bit-identical hsum -> identical argmax. Memory-bound.
// =====================================================================
__global__ __launch_bounds__(256)
void hsum_stream_kernel(const float* __restrict__ Sbuf,
                        const float* __restrict__ MLbuf,
                        float* __restrict__ idx_out)
{
    __shared__ float Ms[NH], Ls[NH];
    __shared__ float rv[4];
    __shared__ int   ri[4];

    const int row = blockIdx.x;          // b*QLEN + q
    const int b   = row >> 11;
    const int qq  = row & 2047;
    const int t   = threadIdx.x;

    if (t < NH) {
        const float* mlp = MLbuf + ((size_t)row * NH + t) * 2;
        Ms[t] = mlp[0];
        Ls[t] = mlp[1];
    }
    __syncthreads();

    // thread t owns k = 4t..4t+3 (slot a) and k = 1024+4t..+3 (slot b)
    float a0 = 0.f, a1 = 0.f, a2 = 0.f, a3 = 0.f;
    float b0 = 0.f, b1 = 0.f, b2 = 0.f, b3 = 0.f;

    #pragma unroll 1
    for (int h = 0; h < NH; ++h) {
        const float* sp = Sbuf + (((size_t)(b * NH + h)) * QLEN + qq) * QLEN;
        float4 va = *(const float4*)&sp[4 * t];
        float4 vb = *(const float4*)&sp[1024 + 4 * t];
        const float Mv = Ms[h], Lv = Ls[h];
        a0 += expf(va.x - Mv) / Lv;
        a1 += expf(va.y - Mv) / Lv;
        a2 += expf(va.z - Mv) / Lv;
        a3 += expf(va.w - Mv) / Lv;
        b0 += expf(vb.x - Mv) / Lv;
        b1 += expf(vb.y - Mv) / Lv;
        b2 += expf(vb.z - Mv) / Lv;
        b3 += expf(vb.w - Mv) / Lv;
    }

    // per-thread best, k ascending -> '>' keeps first index
    float bv = -1.0f; int bk = 0;
    if (a0 > bv) { bv = a0; bk = 4 * t;        }
    if (a1 > bv) { bv = a1; bk = 4 * t + 1;    }
    if (a2 > bv) { bv = a2; bk = 4 * t + 2;    }
    if (a3 > bv) { bv = a3; bk = 4 * t + 3;    }
    if (b0 > bv) { bv = b0; bk = 1024 + 4 * t;     }
    if (b1 > bv) { bv = b1; bk = 1024 + 4 * t + 1; }
    if (b2 > bv) { bv = b2; bk = 1024 + 4 * t + 2; }
    if (b3 > bv) { bv = b3; bk = 1024 + 4 * t + 3; }

    // wave reduce (min-index tie-break)
    #pragma unroll
    for (int off = 32; off >= 1; off >>= 1) {
        float ov = __shfl_down(bv, off, 64);
        int   ok = __shfl_down(bk, off, 64);
        if (ov > bv || (ov == bv && ok < bk)) { bv = ov; bk = ok; }
    }
    if ((t & 63) == 0) { rv[t >> 6] = bv; ri[t >> 6] = bk; }
    __syncthreads();
    if (t == 0) {
        float BV = -1.0f; int BKi = 1 << 30;
        #pragma unroll
        for (int i = 0; i < 4; ++i) {
            float v = rv[i]; int kk = ri[i];
            if (v > BV || (v == BV && kk < BKi)) { BV = v; BKi = kk; }
        }
        idx_out[row] = (float)BKi;
    }
}

// =====================================================================
// Kernel 2b-fallback: head-summed weights -> argmax by recompute
//   (byte-identical to the passing round-6 version; used only when ws
//   is too small for the score buffer).
// =====================================================================
__global__ __launch_bounds__(512, 4)
void hsum_argmax_kernel(const float* __restrict__ Qm, const float* __restrict__ Km,
                        const int* __restrict__ mask, const float* __restrict__ MLbuf,
                        float* __restrict__ idx_out)
{
    __shared__ float qs[QT][DH];
    __shared__ float ks[KC][DH + 1];
    __shared__ float Mh[NH][QT];
    __shared__ float Lh[NH][QT];
    __shared__ int   msk[KC];
    __shared__ float rv[512];
    __shared__ int   ri[512];

    const int b   = blockIdx.y;
    const int q0  = blockIdx.x * QT;
    const int tid = threadIdx.x;
    const int q   = tid >> 5;
    const int kt  = tid & 31;

    if (tid < NH * QT) {
        int h = tid >> 4, qq = tid & 15;
        const float* mlp = MLbuf + (((size_t)(b * QLEN + q0 + qq)) * NH + h) * 2;
        Mh[h][qq] = mlp[0];
        Lh[h][qq] = mlp[1];
    }

    float bv = -1.0f; int bk = 0;
    #pragma unroll 1
    for (int c = 0; c < NCH; ++c) {
        float h0 = 0.f, h1 = 0.f, h2 = 0.f, h3 = 0.f;
        #pragma unroll 1
        for (int h = 0; h < NH; ++h) {
            __syncthreads();
            #pragma unroll
            for (int p = 0; p < 4; ++p) {
                int f4 = tid + p * 512;
                int row = f4 >> 4, c4 = (f4 & 15) << 2;
                const float* Kh = Km + ((size_t)b * NH + h) * QLEN * DH;
                float4 kv = *(const float4*)&Kh[(size_t)(c * KC + row) * DH + c4];
                ks[row][c4] = kv.x; ks[row][c4+1] = kv.y; ks[row][c4+2] = kv.z; ks[row][c4+3] = kv.w;
            }
            if (tid < 256) {
                int row = tid >> 4, c4 = (tid & 15) << 2;
                const float* Qh = Qm + (((size_t)b * NH + h) * QLEN + q0) * DH;
                *(float4*)&qs[row][c4] = *(const float4*)&Qh[(size_t)row * DH + c4];
            }
            if (h == 0 && tid < KC) msk[tid] = mask[b * QLEN + c * KC + tid];
            __syncthreads();

            float sacc[4] = {0.f, 0.f, 0.f, 0.f};
            #pragma unroll
            for (int d0 = 0; d0 < DH; d0 += 8) {
                float qr[8];
                #pragma unroll
                for (int dd = 0; dd < 8; ++dd) qr[dd] = qs[q][d0 + dd];
                #pragma unroll
                for (int jj = 0; jj < 4; ++jj)
                    #pragma unroll
                    for (int dd = 0; dd < 8; ++dd)
                        sacc[jj] = fmaf(qr[dd], ks[kt + 32 * jj][d0 + dd], sacc[jj]);
            }
            const float Mv = Mh[h][q], Lv = Lh[h][q];
            float s0 = msk[kt]      ? sacc[0] : -INFINITY;
            float s1 = msk[kt + 32] ? sacc[1] : -INFINITY;
            float s2 = msk[kt + 64] ? sacc[2] : -INFINITY;
            float s3 = msk[kt + 96] ? sacc[3] : -INFINITY;
            h0 += expf(s0 - Mv) / Lv;
            h1 += expf(s1 - Mv) / Lv;
            h2 += expf(s2 - Mv) / Lv;
            h3 += expf(s3 - Mv) / Lv;
        }
        int kbase = c * KC + kt;
        if (h0 > bv) { bv = h0; bk = kbase;      }
        if (h1 > bv) { bv = h1; bk = kbase + 32; }
        if (h2 > bv) { bv = h2; bk = kbase + 64; }
        if (h3 > bv) { bv = h3; bk = kbase + 96; }
    }

    rv[tid] = bv;
    ri[tid] = bk;
    __syncthreads();
    if (kt == 0) {
        float BV = -1.0f; int BKi = 1 << 30;
        for (int i = 0; i < 32; ++i) {
            float v = rv[q * 32 + i];
            int  kk = ri[q * 32 + i];
            if (v > BV || (v == BV && kk < BKi)) { BV = v; BKi = kk; }
        }
        idx_out[b * QLEN + q0 + q] = (float)BKi;
    }
}

// =====================================================================
// Kernel 3: in-place output projection  IO = IO @ Wo^T + bo
// =====================================================================
#define OPROWS 16

__global__ __launch_bounds__(512, 2)
void outproj_kernel(float* __restrict__ IO, const float* __restrict__ Wo,
                    const float* __restrict__ bo)
{
    __shared__ float ctxs[OPROWS][DIM];    // 64 KB
    __shared__ float wos[64][129];         // 33 KB, +1 pad

    const int m0 = blockIdx.x * OPROWS;
    const int tid = threadIdx.x;
    const int q = tid >> 5, kt = tid & 31;

    #pragma unroll
    for (int p = 0; p < 8; ++p) {
        int f4 = tid + p * 512;
        int row = f4 >> 8;
        int c4 = (f4 & 255) << 2;
        *(float4*)&ctxs[row][c4] = *(const float4*)&IO[(size_t)(m0 + row) * DIM + c4];
    }
    __syncthreads();

    #pragma unroll 1
    for (int oc = 0; oc < DIM / 64; ++oc) {
        float a0 = 0.f, a1 = 0.f;
        #pragma unroll 1
        for (int d0 = 0; d0 < DIM; d0 += 128) {
            #pragma unroll
            for (int p = 0; p < 4; ++p) {
                int f4 = tid + p * 512;
                int row = f4 >> 5, c4 = (f4 & 31) << 2;
                float4 wv = *(const float4*)&Wo[(size_t)(oc * 64 + row) * DIM + d0 + c4];
                wos[row][c4] = wv.x; wos[row][c4+1] = wv.y; wos[row][c4+2] = wv.z; wos[row][c4+3] = wv.w;
            }
            __syncthreads();
            #pragma unroll 8
            for (int dd = 0; dd < 128; ++dd) {
                float cv = ctxs[q][d0 + dd];
                a0 = fmaf(cv, wos[kt][dd],      a0);
                a1 = fmaf(cv, wos[32 + kt][dd], a1);
            }
            __syncthreads();
        }
        int o0 = oc * 64 + kt;
        IO[(size_t)(m0 + q) * DIM + o0]      = a0 + bo[o0];
        IO[(size_t)(m0 + q) * DIM + o0 + 32] = a1 + bo[o0 + 32];
    }
}

// =====================================================================
extern "C" void kernel_launch(void* const* d_in, const int* in_sizes, int n_in,
                              void* d_out, int out_size, void* d_ws, size_t ws_size,
                              hipStream_t stream)
{
    (void)in_sizes; (void)n_in; (void)out_size;
    const float* query = (const float*)d_in[0];
    const int*   mask  = (const int*)  d_in[1];
    const float* Wq = (const float*)d_in[2];
    const float* bq = (const float*)d_in[3];
    const float* Wk = (const float*)d_in[4];
    const float* bk = (const float*)d_in[5];
    const float* Wv = (const float*)d_in[6];
    const float* bv = (const float*)d_in[7];
    const float* Wo = (const float*)d_in[8];
    const float* bo = (const float*)d_in[9];

    float* out = (float*)d_out;
    const size_t NTOK = (size_t)BS * QLEN;         // 8192
    const size_t QKV  = NTOK * DIM;                // 8,388,608 floats each
    const size_t MLSZ = NTOK * NH * 2;             // 262,144 floats
    const size_t SSZ  = (size_t)BS * NH * QLEN * QLEN;  // 268,435,456 floats

    float* Qw = (float*)d_ws;
    float* Kw = Qw + QKV;
    float* Vw = Kw + QKV;
    float* ML = Vw + QKV;
    float* Sb = ML + MLSZ;
    const size_t need_bytes = (3 * QKV + MLSZ + SSZ) * sizeof(float);  // ~1.095 GiB
    const bool use_sbuf = (ws_size >= need_bytes);

    dim3 gemm_grid(DIM / GBN, (BS * QLEN) / GBM);   // (16, 128)
    qkv_gemm<true><<<gemm_grid, dim3(256), 0, stream>>>(query, Wq, bq, Qw, 0.125f);
    qkv_gemm<true><<<gemm_grid, dim3(256), 0, stream>>>(query, Wk, bk, Kw, 1.0f);
    qkv_gemm<false><<<gemm_grid, dim3(256), 0, stream>>>(query, Wv, bv, Vw, 1.0f);

    float* ctx = out;                  // reuse out region as ctx scratch
    float* idx = out + NTOK * DIM;     // argmax output tail

    if (use_sbuf) {
        attn_kernel<true><<<dim3(QLEN / QT2, BS), dim3(512), 0, stream>>>(
            Qw, Kw, Vw, mask, ctx, ML, Sb);
        hsum_stream_kernel<<<dim3((int)NTOK), dim3(256), 0, stream>>>(Sb, ML, idx);
    } else {
        attn_kernel<false><<<dim3(QLEN / QT2, BS), dim3(512), 0, stream>>>(
            Qw, Kw, Vw, mask, ctx, ML, nullptr);
        hsum_argmax_kernel<<<dim3(QLEN / QT, BS), dim3(512), 0, stream>>>(
            Qw, Kw, mask, ML, idx);
    }

    outproj_kernel<<<dim3(NTOK / OPROWS), dim3(512), 0, stream>>>(out, Wo, bo);
}